// Round 8
// baseline (75.852 us; speedup 1.0000x reference)
//
#include <hip/hip_runtime.h>

#define L_SEQ 2048
#define HEADS 16
#define DIM   64
#define TILE  64          // rows per block; 16 rows per wave (4 waves)
#define XROWS 66          // x rows staged: l0-1 .. l0+64
#define XPITCH 68         // f32 pitch: 68 mod 32 = 4 -> 2-way (free) LDS banking

typedef __attribute__((ext_vector_type(8))) short bf16x8;
typedef __attribute__((ext_vector_type(4))) float f32x4;

static __device__ __forceinline__ unsigned short f2bf_rtne(float f) {
    unsigned int u = __builtin_bit_cast(unsigned int, f);
    u += 0x7fffu + ((u >> 16) & 1u);
    return (unsigned short)(u >> 16);
}
// pack hi16(a) | hi16(b)<<16 in ONE v_perm_b32 (truncation rounding — score
// path error budget is ~1000x the threshold sensitivity)
static __device__ __forceinline__ unsigned int pk2(float a, float b) {
    return __builtin_amdgcn_perm(__builtin_bit_cast(unsigned int, b),
                                 __builtin_bit_cast(unsigned int, a), 0x07060302u);
}

__global__ void prep_w_kernel(const float* __restrict__ W, unsigned short* __restrict__ wbf) {
    int i = blockIdx.x * 256 + threadIdx.x;
    if (i < DIM * DIM) wbf[i] = f2bf_rtne(W[i]);
}

static __device__ __forceinline__ bf16x8 load_bfrag(const unsigned short* wbf,
                                                    const float* W, int n, int k0) {
    if (wbf) return *(const bf16x8*)(wbf + n * 64 + k0);
    const float* wr = W + n * 64 + k0;
    float4 w0 = *(const float4*)wr;
    float4 w1 = *(const float4*)(wr + 4);
    uint4 p;
    p.x = pk2(w0.x, w0.y); p.y = pk2(w0.z, w0.w);
    p.z = pk2(w1.x, w1.y); p.w = pk2(w1.z, w1.w);
    return __builtin_bit_cast(bf16x8, p);
}

// R8 = R3's coalesced LDS staging (FETCH 34MB) + R7's wave-independent
// in-register compute (1 barrier total; no dl/el/score LDS buffers).
__global__ __launch_bounds__(256, 8) void betweenness_rope_kernel(
    const float* __restrict__ x, const float* __restrict__ W,
    const unsigned short* __restrict__ wbf, const float* __restrict__ gate,
    float* __restrict__ out)
{
    __shared__ float xs[XROWS * XPITCH];   // ~18 KB

    const int tid  = threadIdx.x;
    const int lane = tid & 63;
    const int wv   = tid >> 6;
    const int la   = lane & 15, lg = lane >> 4;
    const int l0   = blockIdx.x * TILE;
    const int l0w  = l0 + 16 * wv;          // this wave's first output row
    const int h    = blockIdx.y;
    const int b    = blockIdx.z;
    const int bh_off = (b * L_SEQ * HEADS + h) * DIM;

    // ---- P1: stage 66 x rows, fully coalesced (x read from HBM once) ----
    for (int c = tid; c < XROWS * 16; c += 256) {
        int r = c >> 4, q = c & 15;
        int g = max(0, min(L_SEQ - 1, l0 - 1 + r));
        *(float4*)&xs[r * XPITCH + q * 4] =
            *(const float4*)(x + bh_off + g * (HEADS * DIM) + q * 4);
    }
    __syncthreads();   // the ONLY barrier — everything below is wave-local

    // ---- P2: A-fragments from xs; delta row rr = xs[rr+1]-xs[rr] ----
    // mt=0: rows 16wv+la (one per lane); mt=1: boundary row 16wv+16 (all lanes)
    bf16x8 afrag[2][2];
    #pragma unroll
    for (int mt = 0; mt < 2; ++mt) {
        int rr = 16 * wv + (mt ? 16 : la);
        const float* r0 = &xs[rr * XPITCH + lg * 8];
        const float* r1 = r0 + XPITCH;
        #pragma unroll
        for (int kh = 0; kh < 2; ++kh) {
            float4 a0 = *(const float4*)(r0 + kh * 32);
            float4 a1 = *(const float4*)(r0 + kh * 32 + 4);
            float4 b0 = *(const float4*)(r1 + kh * 32);
            float4 b1 = *(const float4*)(r1 + kh * 32 + 4);
            uint4 o;
            o.x = pk2(b0.x - a0.x, b0.y - a0.y);
            o.y = pk2(b0.z - a0.z, b0.w - a0.w);
            o.z = pk2(b1.x - a1.x, b1.y - a1.y);
            o.w = pk2(b1.z - a1.z, b1.w - a1.w);
            afrag[mt][kh] = __builtin_bit_cast(bf16x8, o);
        }
    }

    // ---- P3: E = Delta @ W^T (MFMA) + in-register Gram band (R7-validated) ----
    // D layout: lane holds E[16wv+lg*4+q][16nt+la] in e0[q]; boundary row in e1[0].
    float sq[4] = {0.f, 0.f, 0.f, 0.f};   // -> n1[lg*4+q] after la-reduction
    float pr[4] = {0.f, 0.f, 0.f, 0.f};   // -> g1[lg*4+q]
    float sq16  = 0.f;                    // -> n1[16] (boundary)
    #pragma unroll
    for (int nt = 0; nt < 4; ++nt) {
        bf16x8 b0 = load_bfrag(wbf, W, 16 * nt + la, lg * 8);
        bf16x8 b1 = load_bfrag(wbf, W, 16 * nt + la, lg * 8 + 32);
        f32x4 e0 = {0.f, 0.f, 0.f, 0.f};
        f32x4 e1 = {0.f, 0.f, 0.f, 0.f};
        e0 = __builtin_amdgcn_mfma_f32_16x16x32_bf16(afrag[0][0], b0, e0, 0, 0, 0);
        e0 = __builtin_amdgcn_mfma_f32_16x16x32_bf16(afrag[0][1], b1, e0, 0, 0, 0);
        e1 = __builtin_amdgcn_mfma_f32_16x16x32_bf16(afrag[1][0], b0, e1, 0, 0, 0);
        e1 = __builtin_amdgcn_mfma_f32_16x16x32_bf16(afrag[1][1], b1, e1, 0, 0, 0);
        #pragma unroll
        for (int q = 0; q < 4; ++q) sq[q] = fmaf(e0[q], e0[q], sq[q]);
        sq16  = fmaf(e1[0], e1[0], sq16);
        pr[0] = fmaf(e0[0], e0[1], pr[0]);
        pr[1] = fmaf(e0[1], e0[2], pr[1]);
        pr[2] = fmaf(e0[2], e0[3], pr[2]);
        // row lg*4+4: next lg's e0[0]; lg==3 -> boundary row = own e1[0]
        float up0  = __shfl(e0[0], (lane + 16) & 63);
        float part = (lg == 3) ? e1[0] : up0;
        pr[3] = fmaf(e0[3], part, pr[3]);
    }
    // reduce 9 partials across the 16-lane la-group (xor masks stay in-group)
    #pragma unroll
    for (int m = 1; m < 16; m <<= 1) {
        #pragma unroll
        for (int q = 0; q < 4; ++q) {
            sq[q] += __shfl_xor(sq[q], m, 64);
            pr[q] += __shfl_xor(pr[q], m, 64);
        }
        sq16 += __shfl_xor(sq16, m, 64);
    }
    float sqn3 = __shfl(sq[0], (lane + 16) & 63);   // n1[lg*4+4]
    if (lg == 3) sqn3 = sq16;

    // ---- P4: scores for rows lg*4+q (stay in the producing lane) ----
    const float gate0 = gate[0];
    float flo_[4], frac_[4];
    #pragma unroll
    for (int q = 0; q < 4; ++q) {
        int l = l0w + lg * 4 + q;
        float n1a = sq[q];
        float n1b = (q < 3) ? sq[q + 1] : sqn3;
        float gg  = pr[q];
        float d1a = sqrtf(n1a), d1b = sqrtf(n1b);
        float dd  = sqrtf(fmaxf(n1a + n1b + 2.f * gg, 0.f));  // ||D_r + D_{r+1}||
        float sc  = fmaxf(1.f - ((d1a + d1b) - dd) / fmaxf(dd, 1e-6f), 0.f);
        float bet = (l >= 1 && l <= L_SEQ - 2) ? sc * (1.f / (L_SEQ - 2)) : 0.f;
        float adjust = gate0 * (bet - 0.5f) * 0.1f;
        float ap  = fminf(fmaxf((float)l + adjust, 0.f), (float)(L_SEQ - 1));
        flo_[q]  = floorf(ap);
        frac_[q] = ap - flo_[q];
    }

    // ---- P5: RoPE epilogue — x from LDS, float4 stores (4 rows/instr) ----
    {
        const float fja = __builtin_exp2f(-0.4152410118609203f * (float)(2 * la))
                        * 0.15915494309189535f;     // f_j/(2pi), j=2la
        const float fjb = __builtin_exp2f(-0.4152410118609203f * (float)(2 * la + 1))
                        * 0.15915494309189535f;     // j=2la+1
        const float cfa = __builtin_amdgcn_cosf(fja), sfa = __builtin_amdgcn_sinf(fja);
        const float cfb = __builtin_amdgcn_cosf(fjb), sfb = __builtin_amdgcn_sinf(fjb);
        const float cfma = cfa - 1.0f, cfmb = cfb - 1.0f;
        #pragma unroll
        for (int it = 0; it < 4; ++it) {
            int k = lg * 4 + it;                    // row within wave 0..15
            int l = l0w + k;
            float flo = flo_[it], fr = frac_[it];
            float4 xv = *(const float4*)&xs[(16 * wv + k + 1) * XPITCH + 4 * la];
            // pair a (j=2la)
            float ta  = flo * fja;
            float rva = ta - floorf(ta);
            float cla = __builtin_amdgcn_cosf(rva), sla = __builtin_amdgcn_sinf(rva);
            float ua  = fmaf(fr, cfma, 1.0f);
            float va  = fr * sfa;
            float cia = fmaf(-sla, va, cla * ua);
            float sia = fmaf(cla, va, sla * ua);
            // pair b (j=2la+1)
            float tb  = flo * fjb;
            float rvb = tb - floorf(tb);
            float clb = __builtin_amdgcn_cosf(rvb), slb = __builtin_amdgcn_sinf(rvb);
            float ub  = fmaf(fr, cfmb, 1.0f);
            float vb  = fr * sfb;
            float cib = fmaf(-slb, vb, clb * ub);
            float sib = fmaf(clb, vb, slb * ub);
            float4 o;
            o.x = xv.x * cia - xv.y * sia;
            o.y = fmaf(xv.y, cia, xv.x * sia);
            o.z = xv.z * cib - xv.w * sib;
            o.w = fmaf(xv.w, cib, xv.z * sib);
            *(float4*)(out + bh_off + l * (HEADS * DIM) + 4 * la) = o;
        }
    }
}

extern "C" void kernel_launch(void* const* d_in, const int* in_sizes, int n_in,
                              void* d_out, int out_size, void* d_ws, size_t ws_size,
                              hipStream_t stream) {
    const float* x    = (const float*)d_in[0];
    const float* W    = (const float*)d_in[1];
    const float* gate = (const float*)d_in[3];   // bias cancels in differences
    float* out = (float*)d_out;

    const int B = in_sizes[0] / (L_SEQ * HEADS * DIM);

    unsigned short* wbf = nullptr;
    if (ws_size >= (size_t)(DIM * DIM * sizeof(unsigned short))) {
        wbf = (unsigned short*)d_ws;
        prep_w_kernel<<<16, 256, 0, stream>>>(W, wbf);
    }

    dim3 grid(L_SEQ / TILE, HEADS, B);
    betweenness_rope_kernel<<<grid, 256, 0, stream>>>(x, W, wbf, gate, out);
}

// Round 9
// 50.149 us; speedup vs baseline: 1.5125x; 1.5125x over previous
//
#include <hip/hip_runtime.h>

#define L_SEQ 2048
#define HEADS 16
#define DIM   64
#define TILE  32
#define XROWS 34          // x rows staged: l0-1 .. l0+32
#define XPITCH 68         // f32 pitch (272B)
#define DROWS 48          // delta rows padded to 3 M-tiles of 16

typedef __attribute__((ext_vector_type(8))) short bf16x8;
typedef __attribute__((ext_vector_type(4))) float f32x4;

static __device__ __forceinline__ unsigned short f2bf_rtne(float f) {
    unsigned int u = __builtin_bit_cast(unsigned int, f);
    u += 0x7fffu + ((u >> 16) & 1u);
    return (unsigned short)(u >> 16);
}
// pack hi16(a) | hi16(b)<<16 in ONE v_perm_b32 (truncation rounding — score
// path error budget is ~1000x the threshold sensitivity)
static __device__ __forceinline__ unsigned int pk2(float a, float b) {
    return __builtin_amdgcn_perm(__builtin_bit_cast(unsigned int, b),
                                 __builtin_bit_cast(unsigned int, a), 0x07060302u);
}

// bf16 LDS tiles have 64-ushort (128B) rows -> 16-way conflict unswizzled.
// XOR-swizzle: ushort_col ^ ((row&7)<<3)  == byte ^ ((row&7)<<4).
#define SWZ(row, col) ((row) * 64 + ((col) ^ (((row) & 7) * 8)))

__global__ void prep_w_kernel(const float* __restrict__ W, unsigned short* __restrict__ wbf) {
    int i = blockIdx.x * 256 + threadIdx.x;
    if (i < DIM * DIM) wbf[i] = f2bf_rtne(W[i]);
}

static __device__ __forceinline__ bf16x8 load_bfrag(const unsigned short* wbf,
                                                    const float* W, int n, int k0) {
    if (wbf) return *(const bf16x8*)(wbf + n * 64 + k0);
    const float* wr = W + n * 64 + k0;
    float4 w0 = *(const float4*)wr;
    float4 w1 = *(const float4*)(wr + 4);
    uint4 p;
    p.x = pk2(w0.x, w0.y); p.y = pk2(w0.z, w0.w);
    p.z = pk2(w1.x, w1.y); p.w = pk2(w1.z, w1.w);
    return __builtin_bit_cast(bf16x8, p);
}

// R9 = R3 (best: 40us, clean 34MB/64MB traffic) with the el LDS round-trip
// and Gram-MFMA phase replaced by in-register Gram partials (R7-validated
// math): 4 barriers instead of 6, no bf16(E) repack, no el reads.
__global__ __launch_bounds__(256) void betweenness_rope_kernel(
    const float* __restrict__ x, const float* __restrict__ W,
    const unsigned short* __restrict__ wbf, const float* __restrict__ gate,
    float* __restrict__ out)
{
    __shared__ float xs[XROWS * XPITCH];          // staged x rows (f32)
    __shared__ unsigned short dl[DROWS * 64];     // bf16 delta rows, swizzled
    __shared__ float psq[4][36];                  // per-wave partial ||D_r||^2
    __shared__ float ppr[4][36];                  // per-wave partial D_r.D_{r+1}
    __shared__ float2 fl[TILE];                   // per-row {floor(adj_pos), frac}

    const int tid  = threadIdx.x;
    const int lane = tid & 63;
    const int wv   = tid >> 6;
    const int la   = lane & 15, lg = lane >> 4;
    const int l0   = blockIdx.x * TILE;
    const int h    = blockIdx.y;
    const int b    = blockIdx.z;
    const int bh_off = (b * L_SEQ * HEADS + h) * DIM;

    // ---- P1: stage x rows, coalesced (x read from HBM once) ----
    for (int c = tid; c < XROWS * 16; c += 256) {
        int r = c >> 4, q = c & 15;
        int g = max(0, min(L_SEQ - 1, l0 - 1 + r));
        *(float4*)&xs[r * XPITCH + q * 4] =
            *(const float4*)(x + bh_off + g * (HEADS * DIM) + q * 4);
    }
    __syncthreads();

    // ---- P2: delta rows dl[r] = bf16(xs[r+1]-xs[r]), r=0..32; 33..47 zero ----
    for (int r = tid >> 3; r < DROWS; r += 32) {
        int c0 = (tid & 7) * 8;
        uint4 o = {0u, 0u, 0u, 0u};
        if (r <= 32) {
            float4 a0 = *(float4*)&xs[r * XPITCH + c0];
            float4 a1 = *(float4*)&xs[r * XPITCH + c0 + 4];
            float4 b0 = *(float4*)&xs[(r + 1) * XPITCH + c0];
            float4 b1 = *(float4*)&xs[(r + 1) * XPITCH + c0 + 4];
            o.x = pk2(b0.x - a0.x, b0.y - a0.y);
            o.y = pk2(b0.z - a0.z, b0.w - a0.w);
            o.z = pk2(b1.x - a1.x, b1.y - a1.y);
            o.w = pk2(b1.z - a1.z, b1.w - a1.w);
        }
        *(uint4*)&dl[SWZ(r, c0)] = o;
    }
    __syncthreads();

    // ---- P3: E = Delta @ W^T (nt = wv slice) + in-register Gram partials ----
    {
        bf16x8 b0 = load_bfrag(wbf, W, 16 * wv + la, lg * 8);
        bf16x8 b1 = load_bfrag(wbf, W, 16 * wv + la, lg * 8 + 32);
        f32x4 e0 = {0.f,0.f,0.f,0.f}, e1 = {0.f,0.f,0.f,0.f}, e2 = {0.f,0.f,0.f,0.f};
        {   // mt = 0,1,2 — named accumulators (no runtime-indexed reg arrays)
            bf16x8 aA0 = *(const bf16x8*)&dl[SWZ(la,      lg * 8)];
            bf16x8 aA1 = *(const bf16x8*)&dl[SWZ(la,      lg * 8 + 32)];
            bf16x8 aB0 = *(const bf16x8*)&dl[SWZ(16 + la, lg * 8)];
            bf16x8 aB1 = *(const bf16x8*)&dl[SWZ(16 + la, lg * 8 + 32)];
            bf16x8 aC0 = *(const bf16x8*)&dl[SWZ(32 + la, lg * 8)];
            bf16x8 aC1 = *(const bf16x8*)&dl[SWZ(32 + la, lg * 8 + 32)];
            e0 = __builtin_amdgcn_mfma_f32_16x16x32_bf16(aA0, b0, e0, 0, 0, 0);
            e0 = __builtin_amdgcn_mfma_f32_16x16x32_bf16(aA1, b1, e0, 0, 0, 0);
            e1 = __builtin_amdgcn_mfma_f32_16x16x32_bf16(aB0, b0, e1, 0, 0, 0);
            e1 = __builtin_amdgcn_mfma_f32_16x16x32_bf16(aB1, b1, e1, 0, 0, 0);
            e2 = __builtin_amdgcn_mfma_f32_16x16x32_bf16(aC0, b0, e2, 0, 0, 0);
            e2 = __builtin_amdgcn_mfma_f32_16x16x32_bf16(aC1, b1, e2, 0, 0, 0);
        }
        // lane holds E[16mt+lg*4+q][16wv+la] in e{mt}[q].
        // Gram partials over this wave's 16 columns: rows 0..32 (sq), 0..31 (pr).
        float upA = __shfl(e0[0], (lane + 16) & 63);   // E[4(lg+1)][c] (lg<3)
        float upB = __shfl(e1[0], (lane + 16) & 63);
        float upC = __shfl(e2[0], (lane + 16) & 63);
        float sq0[4], sq1[4], pr0[4], pr1[4], sq2;
        #pragma unroll
        for (int q = 0; q < 4; ++q) { sq0[q] = e0[q] * e0[q]; sq1[q] = e1[q] * e1[q]; }
        sq2 = e2[0] * e2[0];                           // row 32 (valid at lg==0)
        #pragma unroll
        for (int q = 0; q < 3; ++q) { pr0[q] = e0[q] * e0[q + 1]; pr1[q] = e1[q] * e1[q + 1]; }
        pr0[3] = e0[3] * ((lg == 3) ? upB : upA);      // partner row 4lg+4
        pr1[3] = e1[3] * ((lg == 3) ? upC : upB);      // row 31's partner = row 32
        // reduce 17 partials across the 16-lane la-group
        #pragma unroll
        for (int m = 1; m < 16; m <<= 1) {
            #pragma unroll
            for (int q = 0; q < 4; ++q) {
                sq0[q] += __shfl_xor(sq0[q], m, 64);
                sq1[q] += __shfl_xor(sq1[q], m, 64);
                pr0[q] += __shfl_xor(pr0[q], m, 64);
                pr1[q] += __shfl_xor(pr1[q], m, 64);
            }
            sq2 += __shfl_xor(sq2, m, 64);
        }
        if (la == 0) {
            #pragma unroll
            for (int q = 0; q < 4; ++q) {
                psq[wv][4 * lg + q] = sq0[q];
                ppr[wv][4 * lg + q] = pr0[q];
            }
        } else if (la == 1) {
            #pragma unroll
            for (int q = 0; q < 4; ++q) {
                psq[wv][16 + 4 * lg + q] = sq1[q];
                ppr[wv][16 + 4 * lg + q] = pr1[q];
            }
        } else if (la == 2 && lg == 0) {
            psq[wv][32] = sq2;
        }
    }
    __syncthreads();

    // ---- P4: per-row score -> (flo, frac), once per row (32 threads) ----
    if (tid < TILE) {
        const float gate0 = gate[0];
        int r = tid, l = l0 + r;
        float n1a = psq[0][r]     + psq[1][r]     + psq[2][r]     + psq[3][r];
        float n1b = psq[0][r + 1] + psq[1][r + 1] + psq[2][r + 1] + psq[3][r + 1];
        float gg  = ppr[0][r]     + ppr[1][r]     + ppr[2][r]     + ppr[3][r];
        float d1a = sqrtf(n1a), d1b = sqrtf(n1b);
        float dd  = sqrtf(fmaxf(n1a + n1b + 2.f * gg, 0.f));   // ||D_r + D_{r+1}||
        float sc  = fmaxf(1.f - ((d1a + d1b) - dd) / fmaxf(dd, 1e-6f), 0.f);
        float bet = (l >= 1 && l <= L_SEQ - 2) ? sc * (1.f / (L_SEQ - 2)) : 0.f;
        float adjust = gate0 * (bet - 0.5f) * 0.1f;
        float ap  = fminf(fmaxf((float)l + adjust, 0.f), (float)(L_SEQ - 1));
        float flo = floorf(ap);
        fl[r] = make_float2(flo, ap - flo);
    }
    __syncthreads();

    // ---- P5: RoPE epilogue (R3-exact): 1 sincos + rotation, float2 stores ----
    {
        const int j = lane & 31, half = lane >> 5;
        // fjr = f_j / (2*pi): revolutions per position; f_j = 10000^(-j/32)
        const float fjr = __builtin_exp2f(-0.4152410118609203f * (float)j)
                        * 0.15915494309189535f;
        const float cf = __builtin_amdgcn_cosf(fjr);
        const float sf = __builtin_amdgcn_sinf(fjr);
        const float cfm1 = cf - 1.0f;
        const int r0w = wv * 2 + half;                 // base row 0..7
        const float* xbase = &xs[(r0w + 1) * XPITCH + 2 * j];
        float* obase = out + bh_off + (l0 + r0w) * (HEADS * DIM) + 2 * j;
        #pragma unroll
        for (int it = 0; it < 4; ++it) {
            int r = it * 8 + r0w;
            float2 ff = fl[r];
            float t0 = ff.x * fjr;                     // revolutions at lo
            float rv = t0 - floorf(t0);
            float c_lo = __builtin_amdgcn_cosf(rv);
            float s_lo = __builtin_amdgcn_sinf(rv);
            float u = fmaf(ff.y, cfm1, 1.0f);          // (1-frac) + frac*cf
            float v = ff.y * sf;                       // frac*sf
            float ci = fmaf(-s_lo, v, c_lo * u);
            float si = fmaf(c_lo, v, s_lo * u);
            float2 xv = *(const float2*)(xbase + it * 8 * XPITCH);
            float2 o;
            o.x = xv.x * ci - xv.y * si;
            o.y = fmaf(xv.y, ci, xv.x * si);
            *(float2*)(obase + it * 8 * (HEADS * DIM)) = o;
        }
    }
}

extern "C" void kernel_launch(void* const* d_in, const int* in_sizes, int n_in,
                              void* d_out, int out_size, void* d_ws, size_t ws_size,
                              hipStream_t stream) {
    const float* x    = (const float*)d_in[0];
    const float* W    = (const float*)d_in[1];
    const float* gate = (const float*)d_in[3];   // bias cancels in differences
    float* out = (float*)d_out;

    const int B = in_sizes[0] / (L_SEQ * HEADS * DIM);

    unsigned short* wbf = nullptr;
    if (ws_size >= (size_t)(DIM * DIM * sizeof(unsigned short))) {
        wbf = (unsigned short*)d_ws;
        prep_w_kernel<<<16, 256, 0, stream>>>(W, wbf);
    }

    dim3 grid(L_SEQ / TILE, HEADS, B);
    betweenness_rope_kernel<<<grid, 256, 0, stream>>>(x, W, wbf, gate, out);
}

// Round 10
// 42.758 us; speedup vs baseline: 1.7740x; 1.1729x over previous
//
#include <hip/hip_runtime.h>

#define L_SEQ 2048
#define HEADS 16
#define DIM   64
#define TILE  32
#define XROWS 34          // x rows staged: l0-1 .. l0+32
#define XPITCH 68         // f32 pitch (272B)
#define DROWS 48          // delta rows padded to 3 tiles of 16

typedef __attribute__((ext_vector_type(8))) short bf16x8;
typedef __attribute__((ext_vector_type(4))) float f32x4;

// bf16(W^T W), recomputed from W by prep_m_kernel on every launch
// (device global: no hipMalloc, no d_ws dependency, graph-capture safe)
__device__ unsigned short g_mbf[DIM * DIM];

static __device__ __forceinline__ unsigned short f2bf_rtne(float f) {
    unsigned int u = __builtin_bit_cast(unsigned int, f);
    u += 0x7fffu + ((u >> 16) & 1u);
    return (unsigned short)(u >> 16);
}
// pack hi16(a) | hi16(b)<<16 in ONE v_perm_b32 (truncation — score-path error
// budget is ~1000x the threshold sensitivity)
static __device__ __forceinline__ unsigned int pk2(float a, float b) {
    return __builtin_amdgcn_perm(__builtin_bit_cast(unsigned int, b),
                                 __builtin_bit_cast(unsigned int, a), 0x07060302u);
}
static __device__ __forceinline__ float bfhi(unsigned int u) {   // low16 -> f32
    return __builtin_bit_cast(float, u << 16);
}
static __device__ __forceinline__ float bflo(unsigned int u) {   // high16 -> f32
    return __builtin_bit_cast(float, u & 0xffff0000u);
}

// bf16 LDS tiles have 64-ushort (128B) rows -> 16-way conflict unswizzled.
// XOR-swizzle: ushort_col ^ ((row&7)<<3)  == byte ^ ((row&7)<<4).
#define SWZ(row, col) ((row) * 64 + ((col) ^ (((row) & 7) * 8)))

// M[i][j] = sum_e W[e][i]*W[e][j]. 64 blocks x 64 threads; W[e][i] is
// block-uniform (scalar), W[e][j] coalesced.
__global__ void prep_m_kernel(const float* __restrict__ W) {
    const int i = blockIdx.x, j = threadIdx.x;
    float acc = 0.f;
    #pragma unroll 8
    for (int e = 0; e < DIM; ++e)
        acc = fmaf(W[e * DIM + i], W[e * DIM + j], acc);
    g_mbf[i * DIM + j] = f2bf_rtne(acc);
}

// R10 = R3 structure (clean 34MB/64MB traffic) with:
//  - stage+delta merged into one pass (one barrier instead of two)
//  - Gram via F^T = M*Delta^T swapped-operand MFMA: F rows are LANE-LOCAL,
//    dot partners come straight from dl in LDS -> no el buffer, no E repack,
//    no Gram-MFMA phase, only 12 shuffle-adds/thread (R9's 68 was the regression)
//  - 3 barriers total (R3 had 6)
__global__ __launch_bounds__(256) void betweenness_rope_kernel(
    const float* __restrict__ x, const float* __restrict__ gate,
    float* __restrict__ out)
{
    __shared__ float xs[XROWS * XPITCH];          // staged x rows (f32)
    __shared__ unsigned short dl[DROWS * 64];     // bf16 delta rows, swizzled
    __shared__ float psq[4][DROWS];               // per-wave partial ||W d_r||^2
    __shared__ float ppr[4][DROWS];               // per-wave partial (W d_r).(W d_{r+1})
    __shared__ float2 fl[TILE];                   // per-row {floor(adj_pos), frac}

    const int tid  = threadIdx.x;
    const int lane = tid & 63;
    const int wv   = tid >> 6;
    const int la   = lane & 15, lg = lane >> 4;
    const int l0   = blockIdx.x * TILE;
    const int h    = blockIdx.y;
    const int b    = blockIdx.z;
    const int bh_off = (b * L_SEQ * HEADS + h) * DIM;

    // ---- P1: stage xs AND build delta rows in one pass ----
    // items 0..271: (r, c0): stage xs[r]; if r<33 also load x[l0+r] (L1-hot,
    // same line as item r+1) and write dl[r] = bf16(x[l0+r]-x[l0-1+r]).
    // items 272..391: zero dl rows 33..47.
    for (int s = tid; s < 392; s += 256) {
        if (s < 272) {
            int r = s >> 3, c0 = (s & 7) * 8;
            int g = max(0, min(L_SEQ - 1, l0 - 1 + r));
            const float* px = x + bh_off + g * (HEADS * DIM) + c0;
            float4 x0 = *(const float4*)px;
            float4 x1 = *(const float4*)(px + 4);
            *(float4*)&xs[r * XPITCH + c0]     = x0;
            *(float4*)&xs[r * XPITCH + c0 + 4] = x1;
            if (r < 33) {
                int g1 = min(L_SEQ - 1, l0 + r);
                const float* py = x + bh_off + g1 * (HEADS * DIM) + c0;
                float4 y0 = *(const float4*)py;
                float4 y1 = *(const float4*)(py + 4);
                uint4 o;
                o.x = pk2(y0.x - x0.x, y0.y - x0.y);
                o.y = pk2(y0.z - x0.z, y0.w - x0.w);
                o.z = pk2(y1.x - x1.x, y1.y - x1.y);
                o.w = pk2(y1.z - x1.z, y1.w - x1.w);
                *(uint4*)&dl[SWZ(r, c0)] = o;
            }
        } else {
            int z = s - 272;
            int r = 33 + (z >> 3), c0 = (z & 7) * 8;
            uint4 o = {0u, 0u, 0u, 0u};
            *(uint4*)&dl[SWZ(r, c0)] = o;
        }
    }
    __syncthreads();

    // ---- P2: F^T = M @ Delta^T (wave wv owns e-slice 16wv..16wv+15) ----
    // A[m=la][k] = M[16wv+la][k] (row-major slice of g_mbf)
    // B[k][n=la] = Delta[16rt+la][k] (row-major slice of dl)
    // D[m=4lg+q][n=la] = F[16rt+la][16wv+4lg+q]  -> F rows are lane-local.
    {
        const int abase = (16 * wv + la) * 64 + lg * 8;
        bf16x8 ma0 = *(const bf16x8*)&g_mbf[abase];
        bf16x8 ma1 = *(const bf16x8*)&g_mbf[abase + 32];
        const int c = 16 * wv + 4 * lg;     // this lane's 4 e-columns
        #pragma unroll
        for (int rt = 0; rt < 3; ++rt) {
            int br = 16 * rt + la;
            bf16x8 bb0 = *(const bf16x8*)&dl[SWZ(br, lg * 8)];
            bf16x8 bb1 = *(const bf16x8*)&dl[SWZ(br, lg * 8 + 32)];
            f32x4 d = {0.f, 0.f, 0.f, 0.f};
            d = __builtin_amdgcn_mfma_f32_16x16x32_bf16(ma0, bb0, d, 0, 0, 0);
            d = __builtin_amdgcn_mfma_f32_16x16x32_bf16(ma1, bb1, d, 0, 0, 0);
            // band dots: n1p = F[br][c..c+3].delta[br][c..c+3], g1p with row br+1
            uint2 duv = *(const uint2*)&dl[SWZ(br, c)];
            int br1 = min(br + 1, DROWS - 1);          // row 48 clamp (unused result)
            uint2 dvv = *(const uint2*)&dl[SWZ(br1, c)];
            float n1p = d[0] * bfhi(duv.x);
            n1p = fmaf(d[1], bflo(duv.x), n1p);
            n1p = fmaf(d[2], bfhi(duv.y), n1p);
            n1p = fmaf(d[3], bflo(duv.y), n1p);
            float g1p = d[0] * bfhi(dvv.x);
            g1p = fmaf(d[1], bflo(dvv.x), g1p);
            g1p = fmaf(d[2], bfhi(dvv.y), g1p);
            g1p = fmaf(d[3], bflo(dvv.y), g1p);
            // reduce over lg (lanes la, la+16, la+32, la+48): 2 xor steps
            n1p += __shfl_xor(n1p, 16, 64);
            g1p += __shfl_xor(g1p, 16, 64);
            n1p += __shfl_xor(n1p, 32, 64);
            g1p += __shfl_xor(g1p, 32, 64);
            if (lg == 0) { psq[wv][br] = n1p; ppr[wv][br] = g1p; }
        }
    }
    __syncthreads();

    // ---- P3: per-row score -> (flo, frac), once per row ----
    if (tid < TILE) {
        const float gate0 = gate[0];
        int r = tid, l = l0 + r;
        float n1a = psq[0][r]     + psq[1][r]     + psq[2][r]     + psq[3][r];
        float n1b = psq[0][r + 1] + psq[1][r + 1] + psq[2][r + 1] + psq[3][r + 1];
        float gg  = ppr[0][r]     + ppr[1][r]     + ppr[2][r]     + ppr[3][r];
        float d1a = sqrtf(n1a), d1b = sqrtf(n1b);
        float dd  = sqrtf(fmaxf(n1a + n1b + 2.f * gg, 0.f));   // ||E_r + E_{r+1}||
        float sc  = fmaxf(1.f - ((d1a + d1b) - dd) / fmaxf(dd, 1e-6f), 0.f);
        float bet = (l >= 1 && l <= L_SEQ - 2) ? sc * (1.f / (L_SEQ - 2)) : 0.f;
        float adjust = gate0 * (bet - 0.5f) * 0.1f;
        float ap  = fminf(fmaxf((float)l + adjust, 0.f), (float)(L_SEQ - 1));
        float flo = floorf(ap);
        fl[r] = make_float2(flo, ap - flo);
    }
    __syncthreads();

    // ---- P4: RoPE epilogue (R3-exact): 1 sincos + rotation, float2 stores ----
    {
        const int j = lane & 31, half = lane >> 5;
        // fjr = f_j / (2*pi): revolutions per position; f_j = 10000^(-j/32)
        const float fjr = __builtin_exp2f(-0.4152410118609203f * (float)j)
                        * 0.15915494309189535f;
        const float cf = __builtin_amdgcn_cosf(fjr);
        const float sf = __builtin_amdgcn_sinf(fjr);
        const float cfm1 = cf - 1.0f;
        const int r0w = wv * 2 + half;                 // base row 0..7
        const float* xbase = &xs[(r0w + 1) * XPITCH + 2 * j];
        float* obase = out + bh_off + (l0 + r0w) * (HEADS * DIM) + 2 * j;
        #pragma unroll
        for (int it = 0; it < 4; ++it) {
            int r = it * 8 + r0w;
            float2 ff = fl[r];
            float t0 = ff.x * fjr;                     // revolutions at lo
            float rv = t0 - floorf(t0);
            float c_lo = __builtin_amdgcn_cosf(rv);
            float s_lo = __builtin_amdgcn_sinf(rv);
            float u = fmaf(ff.y, cfm1, 1.0f);          // (1-frac) + frac*cf
            float v = ff.y * sf;                       // frac*sf
            float ci = fmaf(-s_lo, v, c_lo * u);
            float si = fmaf(c_lo, v, s_lo * u);
            float2 xv = *(const float2*)(xbase + it * 8 * XPITCH);
            float2 o;
            o.x = xv.x * ci - xv.y * si;
            o.y = fmaf(xv.y, ci, xv.x * si);
            *(float2*)(obase + it * 8 * (HEADS * DIM)) = o;
        }
    }
}

extern "C" void kernel_launch(void* const* d_in, const int* in_sizes, int n_in,
                              void* d_out, int out_size, void* d_ws, size_t ws_size,
                              hipStream_t stream) {
    const float* x    = (const float*)d_in[0];
    const float* W    = (const float*)d_in[1];
    const float* gate = (const float*)d_in[3];   // bias cancels in differences
    float* out = (float*)d_out;

    const int B = in_sizes[0] / (L_SEQ * HEADS * DIM);

    prep_m_kernel<<<DIM, DIM, 0, stream>>>(W);   // M = W^T W into device global

    dim3 grid(L_SEQ / TILE, HEADS, B);
    betweenness_rope_kernel<<<grid, 256, 0, stream>>>(x, gate, out);
}